// Round 3
// baseline (519.673 us; speedup 1.0000x reference)
//
#include <hip/hip_runtime.h>

#define HH 8
#define LL 256
#define CC 32
#define VT_STRIDE 264   // padded sk2 stride for V^T, multiple of 8 (b128 align)
#define PC_STRIDE 40    // per-wave P chunk stride, multiple of 8 (b128 align)

typedef _Float16 f16x8 __attribute__((ext_vector_type(8)));
typedef _Float16 f16x4 __attribute__((ext_vector_type(4)));
typedef float    f32x4 __attribute__((ext_vector_type(4)));

// Transpose bias (B=1, s2, sk2, H) -> biasT [H][s2][sk2] so the main kernel's
// bias loads become lane-coalesced float4.
__global__ __launch_bounds__(256)
void bias_transpose(const float* __restrict__ bias, float* __restrict__ biasT) {
    const int g = blockIdx.x * 256 + threadIdx.x;   // g = h*65536 + s2*256 + sk2
    const int h = g >> 16;
    const int s2sk2 = g & 65535;
    biasT[g] = bias[(s2sk2 << 3) | h];
}

// Transpose gate (1, s1, s2, C*H) -> gateT [H][s1*s2][C] via LDS tile so the
// main kernel's gate reads hit full cache lines instead of stride-32B scalars
// (which over-fetched ~8x = ~450-500 MB of L2 fill).
__global__ __launch_bounds__(256)
void gate_transpose(const float* __restrict__ gate, float* __restrict__ gateT) {
    __shared__ float t[32 * 264];                 // 32 rows x 256ch, pad to 264
    const int row0 = blockIdx.x * 32;             // flattened s1*256+s2 row base
    const int tid  = threadIdx.x;
    #pragma unroll
    for (int i = 0; i < 8; ++i) {
        const int idx = i * 256 + tid;            // f32x4 index over 32x64
        const int r   = idx >> 6;
        const int c4  = idx & 63;
        f32x4 f = __builtin_nontemporal_load(
            ((const f32x4*)gate) + (size_t)(row0 + r) * 64 + c4);
        *(f32x4*)&t[r * 264 + c4 * 4] = f;
    }
    __syncthreads();
    const int r  = tid >> 3;                      // 0..31 tile row
    const int c4 = tid & 7;                       // output f32x4 within row
    #pragma unroll
    for (int h = 0; h < HH; ++h) {
        f32x4 o;
        o[0] = t[r * 264 + (c4 * 4 + 0) * 8 + h];
        o[1] = t[r * 264 + (c4 * 4 + 1) * 8 + h];
        o[2] = t[r * 264 + (c4 * 4 + 2) * 8 + h];
        o[3] = t[r * 264 + (c4 * 4 + 3) * 8 + h];
        // plain store: gateT is consumed by the next kernel; keep it in L2
        *(((f32x4*)gateT) + ((size_t)h * (LL * LL) + row0 + r) * 8 + c4) = o;
    }
}

// Flash-split over sk2 (two 128-wide halves, online softmax), ~70 live regs.
// (256,4): cap 128 regs, 4 blocks/CU at 38.4 KB LDS.
__global__ __launch_bounds__(256, 4)
void triattn(const float* __restrict__ q, const float* __restrict__ k,
             const float* __restrict__ v, const float* __restrict__ bias,
             const float* __restrict__ biasT,   // may be null -> fallback path
             const float* __restrict__ gate,    // raw layout (fallback)
             const float* __restrict__ gateT,   // may be null -> fallback path
             float* __restrict__ out) {
    __shared__ _Float16 Klds[LL * CC];            // [sk2][32]      16384 B
    __shared__ _Float16 Vt[CC * VT_STRIDE];       // [c][sk2]       16896 B
    __shared__ _Float16 Pc[4][16 * PC_STRIDE];    // per-wave chunk  5120 B

    const int h    = blockIdx.y;
    const int s1   = blockIdx.x;
    const int tid  = threadIdx.x;
    const int wave = tid >> 6;
    const int lane = tid & 63;
    const int n16  = lane & 15;
    const int quad = lane >> 4;

    const size_t base = ((size_t)(h * LL + s1)) * (LL * CC);
    const float* qb = q + base;
    const float* kb = k + base;
    const float* vb = v + base;
    float*       ob = out + base;
    const float* gateb  = gate + ((size_t)s1 * (LL * CC * HH)) + h;
    const float* gateTb = gateT ? (gateT + ((size_t)(h * LL + s1) * LL) * CC) : nullptr;

    // ---- issue strip-0 Q fragment loads early (hidden under K/V staging) ----
    f32x4 qA, qB;
    {
        const f32x4* qr4 = (const f32x4*)(qb + (size_t)(wave * 64 + n16) * CC + quad * 8);
        qA = __builtin_nontemporal_load(qr4);
        qB = __builtin_nontemporal_load(qr4 + 1);
    }

    // ---- stage K and V^T into LDS as fp16 (NT loads: stream-once, read-only) ----
    const f32x4* k4 = (const f32x4*)kb;
    const f32x4* v4 = (const f32x4*)vb;
    #pragma unroll
    for (int i = 0; i < 8; ++i) {
        const int idx = tid + i * 256;        // f32x4 index over 2048
        const int row = idx >> 3;             // sk2
        const int c0  = (idx & 7) * 4;        // channel base
        f32x4 f = __builtin_nontemporal_load(k4 + idx);
        f16x4 kv4 = { (_Float16)f[0], (_Float16)f[1], (_Float16)f[2], (_Float16)f[3] };
        *(f16x4*)&Klds[row * CC + c0] = kv4;
        f32x4 g = __builtin_nontemporal_load(v4 + idx);
        _Float16* vd = &Vt[c0 * VT_STRIDE + row];
        vd[0]             = (_Float16)g[0];
        vd[VT_STRIDE]     = (_Float16)g[1];
        vd[2 * VT_STRIDE] = (_Float16)g[2];
        vd[3 * VT_STRIDE] = (_Float16)g[3];
    }
    __syncthreads();

    _Float16* pw = Pc[wave];

    #pragma unroll 1
    for (int si = 0; si < 4; ++si) {
        const int strip = wave * 4 + si;
        const int r0 = strip * 16;            // s2 base for this strip

        // Q as B-operand fragment: B[k=c=quad*8+j][n=s2=n16]
        f16x8 qf;
        qf[0] = (_Float16)qA[0]; qf[1] = (_Float16)qA[1];
        qf[2] = (_Float16)qA[2]; qf[3] = (_Float16)qA[3];
        qf[4] = (_Float16)qB[0]; qf[5] = (_Float16)qB[1];
        qf[6] = (_Float16)qB[2]; qf[7] = (_Float16)qB[3];

        // prefetch next strip's Q (consumed at next iteration's top)
        if (si < 3) {
            const f32x4* qr4 = (const f32x4*)(qb + (size_t)(r0 + 16 + n16) * CC + quad * 8);
            qA = __builtin_nontemporal_load(qr4);
            qB = __builtin_nontemporal_load(qr4 + 1);
        }

        f32x4 o0 = {0.f, 0.f, 0.f, 0.f}, o1 = {0.f, 0.f, 0.f, 0.f};
        float mrow = 0.f;   // valid after hh=0
        float srow = 0.f;

        #pragma unroll
        for (int hh = 0; hh < 2; ++hh) {
            // ---- S^T half: acc[t] row = sk2 = (hh*8+t)*16+quad*4+r, col = s2 = n16 ----
            f32x4 acc[8];
            #pragma unroll
            for (int t = 0; t < 8; ++t) {
                f16x8 kf = *(const f16x8*)&Klds[((hh * 8 + t) * 16 + n16) * CC + quad * 8];
                f32x4 z = {0.f, 0.f, 0.f, 0.f};
                acc[t] = __builtin_amdgcn_mfma_f32_16x16x32_f16(kf, qf, z, 0, 0, 0);
            }

            // ---- bias add: bias[s2 = r0+n16][sk2 = (hh*8+t)*16+quad*4+r] ----
            if (biasT) {
                const f32x4* bb = (const f32x4*)(biasT + ((size_t)h << 16)
                                                 + (size_t)(r0 + n16) * LL) + quad;
                #pragma unroll
                for (int t = 0; t < 8; ++t) {
                    f32x4 bv = bb[(hh * 8 + t) * 4];
                    acc[t][0] += bv[0]; acc[t][1] += bv[1];
                    acc[t][2] += bv[2]; acc[t][3] += bv[3];
                }
            } else {
                const float* bb = bias + h + ((size_t)(r0 + n16) * LL + quad * 4) * HH;
                #pragma unroll
                for (int t = 0; t < 8; ++t)
                    #pragma unroll
                    for (int r = 0; r < 4; ++r)
                        acc[t][r] += bb[((hh * 8 + t) * 16 + r) * HH];
            }

            // ---- local row-max (rows = s2 = n16; quad-uniform after shuffles) ----
            f32x4 mv = acc[0];
            #pragma unroll
            for (int t = 1; t < 8; ++t) {
                mv[0] = fmaxf(mv[0], acc[t][0]); mv[1] = fmaxf(mv[1], acc[t][1]);
                mv[2] = fmaxf(mv[2], acc[t][2]); mv[3] = fmaxf(mv[3], acc[t][3]);
            }
            float ml = fmaxf(fmaxf(mv[0], mv[1]), fmaxf(mv[2], mv[3]));
            ml = fmaxf(ml, __shfl_xor(ml, 16));
            ml = fmaxf(ml, __shfl_xor(ml, 32));

            const float mNew = (hh == 0) ? ml : fmaxf(mrow, ml);

            // ---- exp + local sum ----
            f32x4 sv = {0.f, 0.f, 0.f, 0.f};
            #pragma unroll
            for (int t = 0; t < 8; ++t) {
                #pragma unroll
                for (int r = 0; r < 4; ++r) {
                    float p = exp2f((acc[t][r] - mNew) * 1.44269504f);
                    acc[t][r] = p;
                    sv[r] += p;
                }
            }
            float sl = (sv[0] + sv[1]) + (sv[2] + sv[3]);
            sl += __shfl_xor(sl, 16);
            sl += __shfl_xor(sl, 32);

            if (hh == 0) {
                srow = sl;
            } else {
                const float alpha = exp2f((mrow - mNew) * 1.44269504f);
                srow = srow * alpha + sl;
                // rescale o BEFORE accumulating this half's PV
                #pragma unroll
                for (int r = 0; r < 4; ++r) {
                    const float ar = __shfl(alpha, quad * 4 + r);
                    o0[r] *= ar; o1[r] *= ar;
                }
            }
            mrow = mNew;

            // ---- PV for this half: kk chunks of 32 sk2 ----
            #pragma unroll
            for (int kl = 0; kl < 4; ++kl) {
                const int kg = hh * 4 + kl;
                const int t0 = 2 * kl, t1 = 2 * kl + 1;
                f16x4 pa = { (_Float16)acc[t0][0], (_Float16)acc[t0][1],
                             (_Float16)acc[t0][2], (_Float16)acc[t0][3] };
                f16x4 pb = { (_Float16)acc[t1][0], (_Float16)acc[t1][1],
                             (_Float16)acc[t1][2], (_Float16)acc[t1][3] };
                *(f16x4*)&pw[n16 * PC_STRIDE + quad * 4]      = pa;
                *(f16x4*)&pw[n16 * PC_STRIDE + 16 + quad * 4] = pb;
                // same-wave DS ops are in-order: read sees this chunk's data,
                // and the next chunk's overwrite cannot pass this read.
                f16x8 pf  = *(const f16x8*)&pw[n16 * PC_STRIDE + quad * 8];
                f16x8 vf0 = *(const f16x8*)&Vt[n16 * VT_STRIDE + kg * 32 + quad * 8];
                f16x8 vf1 = *(const f16x8*)&Vt[(16 + n16) * VT_STRIDE + kg * 32 + quad * 8];
                o0 = __builtin_amdgcn_mfma_f32_16x16x32_f16(pf, vf0, o0, 0, 0, 0);
                o1 = __builtin_amdgcn_mfma_f32_16x16x32_f16(pf, vf1, o1, 0, 0, 0);
            }
        }

        // ---- epilogue: normalize (shuffled inv), gate, store ----
        const float inv = 1.f / srow;   // per s2-row (indexed by n16)
        #pragma unroll
        for (int r = 0; r < 4; ++r) {
            const float wr = __shfl(inv, quad * 4 + r);
            const int s2 = r0 + quad * 4 + r;
            float g0, g1;
            if (gateTb) {
                // coalesced: quad's 16 lanes read one 64B segment; both halves
                // of each 128B gateT line are consumed by the pair of loads
                g0 = gateTb[(size_t)s2 * CC + n16];
                g1 = gateTb[(size_t)s2 * CC + 16 + n16];
            } else {
                g0 = gateb[(s2 * CC + n16) * HH];
                g1 = gateb[(s2 * CC + 16 + n16) * HH];
            }
            ob[(size_t)s2 * CC + n16]      = o0[r] * wr * g0;
            ob[(size_t)s2 * CC + 16 + n16] = o1[r] * wr * g1;
        }
    }
}

extern "C" void kernel_launch(void* const* d_in, const int* in_sizes, int n_in,
                              void* d_out, int out_size, void* d_ws, size_t ws_size,
                              hipStream_t stream) {
    const float* q    = (const float*)d_in[0];
    const float* k    = (const float*)d_in[1];
    const float* v    = (const float*)d_in[2];
    const float* bias = (const float*)d_in[3];
    const float* gate = (const float*)d_in[4];
    float* out = (float*)d_out;

    const size_t biasT_sz = (size_t)HH * LL * LL * sizeof(float);        // 2 MB
    const size_t gateT_sz = (size_t)HH * LL * LL * CC * sizeof(float);   // 64 MB

    float* biasT = nullptr;
    float* gateT = nullptr;
    if (ws_size >= biasT_sz) {
        biasT = (float*)d_ws;
        bias_transpose<<<dim3((HH * LL * LL) / 256), 256, 0, stream>>>(bias, biasT);
    }
    if (biasT && ws_size >= biasT_sz + gateT_sz) {
        gateT = biasT + (size_t)HH * LL * LL;
        gate_transpose<<<dim3((LL * LL) / 32), 256, 0, stream>>>(gate, gateT);
    }
    dim3 grid(LL, HH);
    triattn<<<grid, 256, 0, stream>>>(q, k, v, bias, biasT, gate, gateT, out);
}

// Round 4
// 505.171 us; speedup vs baseline: 1.0287x; 1.0287x over previous
//
#include <hip/hip_runtime.h>

#define HH 8
#define LL 256
#define CC 32
#define NS1 2           // s1 values per block (bias L2-reuse tiling)
#define VT_STRIDE 264   // padded sk2 stride for V^T, multiple of 8 (b128 align)
#define PC_STRIDE 40    // per-wave P chunk stride, multiple of 8 (b128 align)

typedef _Float16 f16x8 __attribute__((ext_vector_type(8)));
typedef _Float16 f16x4 __attribute__((ext_vector_type(4)));
typedef float    f32x4 __attribute__((ext_vector_type(4)));

// Transpose bias (B=1, s2, sk2, H) -> biasT [H][s2][sk2] so the main kernel's
// bias loads become lane-coalesced float4.
__global__ __launch_bounds__(256)
void bias_transpose(const float* __restrict__ bias, float* __restrict__ biasT) {
    const int g = blockIdx.x * 256 + threadIdx.x;   // g = h*65536 + s2*256 + sk2
    const int h = g >> 16;
    const int s2sk2 = g & 65535;
    biasT[g] = bias[(s2sk2 << 3) | h];
}

// Flash-split over sk2 (two 128-wide halves, online softmax), ~70 live regs.
// (256,4): cap 128 regs, 4 blocks/CU at 38.4 KB LDS.
// NS1=2: two s1 per block -> biasT[h] slice (256KB) demanded once per 2 s1,
// second pass temporally adjacent => L2 hit; bias HBM demand 512->~256 MB.
__global__ __launch_bounds__(256, 4)
void triattn(const float* __restrict__ q, const float* __restrict__ k,
             const float* __restrict__ v, const float* __restrict__ bias,
             const float* __restrict__ biasT,   // may be null -> fallback path
             const float* __restrict__ gate, float* __restrict__ out) {
    __shared__ _Float16 Klds[LL * CC];            // [sk2][32]      16384 B
    __shared__ _Float16 Vt[CC * VT_STRIDE];       // [c][sk2]       16896 B
    __shared__ _Float16 Pc[4][16 * PC_STRIDE];    // per-wave chunk  5120 B

    const int h    = blockIdx.y;
    const int s1b  = blockIdx.x * NS1;
    const int tid  = threadIdx.x;
    const int wave = tid >> 6;
    const int lane = tid & 63;
    const int n16  = lane & 15;
    const int quad = lane >> 4;

    _Float16* pw = Pc[wave];

    #pragma unroll 1
    for (int s1i = 0; s1i < NS1; ++s1i) {
        const int s1 = s1b + s1i;
        const size_t base = ((size_t)(h * LL + s1)) * (LL * CC);
        const float* qb = q + base;
        const float* kb = k + base;
        const float* vb = v + base;
        float*       ob = out + base;
        const float* gateb = gate + ((size_t)s1 * (LL * CC * HH)) + h;

        // ---- issue strip-0 Q loads early (hidden under K/V staging) ----
        f32x4 qA, qB;
        {
            const f32x4* qr4 = (const f32x4*)(qb + (size_t)(wave * 64 + n16) * CC + quad * 8);
            qA = __builtin_nontemporal_load(qr4);
            qB = __builtin_nontemporal_load(qr4 + 1);
        }

        // ---- stage K and V^T into LDS as fp16 (NT: stream-once, read-only) ----
        const f32x4* k4 = (const f32x4*)kb;
        const f32x4* v4 = (const f32x4*)vb;
        #pragma unroll
        for (int i = 0; i < 8; ++i) {
            const int idx = tid + i * 256;        // f32x4 index over 2048
            const int row = idx >> 3;             // sk2
            const int c0  = (idx & 7) * 4;        // channel base
            f32x4 f = __builtin_nontemporal_load(k4 + idx);
            f16x4 kv4 = { (_Float16)f[0], (_Float16)f[1], (_Float16)f[2], (_Float16)f[3] };
            *(f16x4*)&Klds[row * CC + c0] = kv4;
            f32x4 g = __builtin_nontemporal_load(v4 + idx);
            _Float16* vd = &Vt[c0 * VT_STRIDE + row];
            vd[0]             = (_Float16)g[0];
            vd[VT_STRIDE]     = (_Float16)g[1];
            vd[2 * VT_STRIDE] = (_Float16)g[2];
            vd[3 * VT_STRIDE] = (_Float16)g[3];
        }
        __syncthreads();

        #pragma unroll 1
        for (int si = 0; si < 4; ++si) {
            const int strip = wave * 4 + si;
            const int r0 = strip * 16;            // s2 base for this strip

            // Q as B-operand fragment: B[k=c=quad*8+j][n=s2=n16]
            f16x8 qf;
            qf[0] = (_Float16)qA[0]; qf[1] = (_Float16)qA[1];
            qf[2] = (_Float16)qA[2]; qf[3] = (_Float16)qA[3];
            qf[4] = (_Float16)qB[0]; qf[5] = (_Float16)qB[1];
            qf[6] = (_Float16)qB[2]; qf[7] = (_Float16)qB[3];

            // prefetch next strip's Q (consumed at next iteration's top)
            if (si < 3) {
                const f32x4* qr4 = (const f32x4*)(qb + (size_t)(r0 + 16 + n16) * CC + quad * 8);
                qA = __builtin_nontemporal_load(qr4);
                qB = __builtin_nontemporal_load(qr4 + 1);
            }

            f32x4 o0 = {0.f, 0.f, 0.f, 0.f}, o1 = {0.f, 0.f, 0.f, 0.f};
            float mrow = 0.f;   // valid after hh=0
            float srow = 0.f;

            #pragma unroll
            for (int hh = 0; hh < 2; ++hh) {
                // ---- S^T half: acc[t] row=sk2=(hh*8+t)*16+quad*4+r, col=s2=n16 ----
                f32x4 acc[8];
                #pragma unroll
                for (int t = 0; t < 8; ++t) {
                    f16x8 kf = *(const f16x8*)&Klds[((hh * 8 + t) * 16 + n16) * CC + quad * 8];
                    f32x4 z = {0.f, 0.f, 0.f, 0.f};
                    acc[t] = __builtin_amdgcn_mfma_f32_16x16x32_f16(kf, qf, z, 0, 0, 0);
                }

                // ---- bias add: bias[s2 = r0+n16][sk2 = (hh*8+t)*16+quad*4+r] ----
                if (biasT) {
                    const f32x4* bb = (const f32x4*)(biasT + ((size_t)h << 16)
                                                     + (size_t)(r0 + n16) * LL) + quad;
                    #pragma unroll
                    for (int t = 0; t < 8; ++t) {
                        f32x4 bv = bb[(hh * 8 + t) * 4];
                        acc[t][0] += bv[0]; acc[t][1] += bv[1];
                        acc[t][2] += bv[2]; acc[t][3] += bv[3];
                    }
                } else {
                    const float* bb = bias + h + ((size_t)(r0 + n16) * LL + quad * 4) * HH;
                    #pragma unroll
                    for (int t = 0; t < 8; ++t)
                        #pragma unroll
                        for (int r = 0; r < 4; ++r)
                            acc[t][r] += bb[((hh * 8 + t) * 16 + r) * HH];
                }

                // ---- local row-max (rows = s2 = n16; quad-uniform after shuffles) ----
                f32x4 mv = acc[0];
                #pragma unroll
                for (int t = 1; t < 8; ++t) {
                    mv[0] = fmaxf(mv[0], acc[t][0]); mv[1] = fmaxf(mv[1], acc[t][1]);
                    mv[2] = fmaxf(mv[2], acc[t][2]); mv[3] = fmaxf(mv[3], acc[t][3]);
                }
                float ml = fmaxf(fmaxf(mv[0], mv[1]), fmaxf(mv[2], mv[3]));
                ml = fmaxf(ml, __shfl_xor(ml, 16));
                ml = fmaxf(ml, __shfl_xor(ml, 32));

                const float mNew = (hh == 0) ? ml : fmaxf(mrow, ml);

                // ---- exp + local sum ----
                f32x4 sv = {0.f, 0.f, 0.f, 0.f};
                #pragma unroll
                for (int t = 0; t < 8; ++t) {
                    #pragma unroll
                    for (int r = 0; r < 4; ++r) {
                        float p = exp2f((acc[t][r] - mNew) * 1.44269504f);
                        acc[t][r] = p;
                        sv[r] += p;
                    }
                }
                float sl = (sv[0] + sv[1]) + (sv[2] + sv[3]);
                sl += __shfl_xor(sl, 16);
                sl += __shfl_xor(sl, 32);

                if (hh == 0) {
                    srow = sl;
                } else {
                    const float alpha = exp2f((mrow - mNew) * 1.44269504f);
                    srow = srow * alpha + sl;
                    // rescale o BEFORE accumulating this half's PV
                    #pragma unroll
                    for (int r = 0; r < 4; ++r) {
                        const float ar = __shfl(alpha, quad * 4 + r);
                        o0[r] *= ar; o1[r] *= ar;
                    }
                }
                mrow = mNew;

                // ---- PV for this half: kk chunks of 32 sk2 ----
                #pragma unroll
                for (int kl = 0; kl < 4; ++kl) {
                    const int kg = hh * 4 + kl;
                    const int t0 = 2 * kl, t1 = 2 * kl + 1;
                    f16x4 pa = { (_Float16)acc[t0][0], (_Float16)acc[t0][1],
                                 (_Float16)acc[t0][2], (_Float16)acc[t0][3] };
                    f16x4 pb = { (_Float16)acc[t1][0], (_Float16)acc[t1][1],
                                 (_Float16)acc[t1][2], (_Float16)acc[t1][3] };
                    *(f16x4*)&pw[n16 * PC_STRIDE + quad * 4]      = pa;
                    *(f16x4*)&pw[n16 * PC_STRIDE + 16 + quad * 4] = pb;
                    // same-wave DS ops are in-order: read sees this chunk's data,
                    // and the next chunk's overwrite cannot pass this read.
                    f16x8 pf  = *(const f16x8*)&pw[n16 * PC_STRIDE + quad * 8];
                    f16x8 vf0 = *(const f16x8*)&Vt[n16 * VT_STRIDE + kg * 32 + quad * 8];
                    f16x8 vf1 = *(const f16x8*)&Vt[(16 + n16) * VT_STRIDE + kg * 32 + quad * 8];
                    o0 = __builtin_amdgcn_mfma_f32_16x16x32_f16(pf, vf0, o0, 0, 0, 0);
                    o1 = __builtin_amdgcn_mfma_f32_16x16x32_f16(pf, vf1, o1, 0, 0, 0);
                }
            }

            // ---- epilogue: normalize (shuffled inv), gate, NT store ----
            const float inv = 1.f / srow;   // per s2-row (indexed by n16)
            #pragma unroll
            for (int r = 0; r < 4; ++r) {
                const float wr = __shfl(inv, quad * 4 + r);
                const int s2 = r0 + quad * 4 + r;
                // gate: plain loads — 8 h-blocks on the same XCD share these
                // lines via L2 (s1 stride 256 ≡ 0 mod 8 XCDs)
                const float g0 = gateb[(s2 * CC + n16) * HH];
                const float g1 = gateb[(s2 * CC + 16 + n16) * HH];
                // out: NT stores — zero reuse; don't let write-allocations
                // evict the biasT working set from L2
                __builtin_nontemporal_store(o0[r] * wr * g0, &ob[(size_t)s2 * CC + n16]);
                __builtin_nontemporal_store(o1[r] * wr * g1, &ob[(size_t)s2 * CC + 16 + n16]);
            }
        }
        // protect LDS (K/V) against next s1 iteration's re-staging
        __syncthreads();
    }
}

extern "C" void kernel_launch(void* const* d_in, const int* in_sizes, int n_in,
                              void* d_out, int out_size, void* d_ws, size_t ws_size,
                              hipStream_t stream) {
    const float* q    = (const float*)d_in[0];
    const float* k    = (const float*)d_in[1];
    const float* v    = (const float*)d_in[2];
    const float* bias = (const float*)d_in[3];
    const float* gate = (const float*)d_in[4];
    float* out = (float*)d_out;

    float* biasT = nullptr;
    if (ws_size >= (size_t)HH * LL * LL * sizeof(float)) {
        biasT = (float*)d_ws;
        bias_transpose<<<dim3((HH * LL * LL) / 256), 256, 0, stream>>>(bias, biasT);
    }
    dim3 grid(LL / NS1, HH);
    triattn<<<grid, 256, 0, stream>>>(q, k, v, bias, biasT, gate, out);
}